// Round 8
// baseline (350.153 us; speedup 1.0000x reference)
//
#include <hip/hip_runtime.h>

// GRU stack, hidden_size=1, 6 layers, B=4096, T=2048, D=8.
// One 8-lane group per batch element PAIR: lanes 0..5 = layers (skewed
// pipeline), chain A = batch b, chain B = batch b+2048, software-interleaved
// so chain B's instructions fill chain A's dependency-chain stalls (the wave
// is alone on its SIMD; round 6/7 showed ~272cy/step = mostly stall).
// Layer l at iteration i handles t = i - l; previous layer's h arrives via
// DPP row_shr:1 (row-crossing lanes 0,16,32,48 are all l==0 -> ignore nbr).
//
// Layer-0 input projection: once per 8-step chunk, distributed across the
// group's 8 lanes (lane j = step j), broadcast via ds_swizzle (BitMode
// src=(lane&0x18)|s, constant pattern), selected vs B1 off-chain.
// x per lane = 2 float4/chunk/chain; 4-buffer distance-2 register pipeline
// (load c+3 / prep c+1 / run c), all arrays statically indexed (no scratch).
//
// Gate math in exp2 form, constants pre-folded:
//   sigmoid(p) = rcp(1 + exp2(c1*p)),  c1 = -log2(e)
//   tanh(y)    = 2*rcp(1 + exp2(c2*y)) - 1,  c2 = -2*log2(e)

#define T_LEN 2048
#define T8    (T_LEN * 8)
#define NCH   256          // 8-step chunks

__device__ __forceinline__ float dpp_shr1(float v) {
    int i = __builtin_bit_cast(int, v);
    int r = __builtin_amdgcn_update_dpp(0, i, 0x111 /*row_shr:1*/, 0xF, 0xF, true);
    return __builtin_bit_cast(float, r);
}

__global__ __launch_bounds__(64)
__attribute__((amdgpu_waves_per_eu(1, 1)))
void gru_scan(const float* __restrict__ x,
              const float* __restrict__ Wih0,   // [3][8]
              const float* __restrict__ Wrest,  // [5][3]
              const float* __restrict__ Whh,    // [6][3]
              const float* __restrict__ bih,    // [6][3]
              const float* __restrict__ bhh,    // [6][3]
              float* __restrict__ out)          // [B]
{
    const int lane = threadIdx.x & 63;   // block = 1 wave
    const int l    = lane & 7;           // 0..5 layers; 6,7 proj-only helpers
    const int g    = lane >> 3;          // group within wave
    const int bA   = blockIdx.x * 8 + g; // chain A batch
    const int bB   = bA + 2048;          // chain B batch

    const float c1 = -1.44269504088896340736f;   // -log2(e)
    const float c2 = 2.0f * c1;

    const int  lidx = l < 6 ? l : 5;
    const bool lz   = (l == 0);
    const float m1  = lz ? 0.0f : 1.0f;

    const float whpr = c1 * Whh[lidx * 3 + 0];
    const float whpz = c1 * Whh[lidx * 3 + 1];
    const float whpn = c2 * Whh[lidx * 3 + 2];
    const float bhpn = c2 * bhh[lidx * 3 + 2];

    const int ir = lidx >= 1 ? lidx - 1 : 0;
    const float W1r = m1 * c1 * Wrest[ir * 3 + 0];
    const float W1z = m1 * c1 * Wrest[ir * 3 + 1];
    const float W1n = m1 * c2 * Wrest[ir * 3 + 2];
    const float B1r = c1 * (bih[lidx * 3 + 0] + bhh[lidx * 3 + 0]);
    const float B1z = c1 * (bih[lidx * 3 + 1] + bhh[lidx * 3 + 1]);
    const float B1n = c2 *  bih[lidx * 3 + 2];

    // layer-0 constants (uniform across lanes) for the distributed projection
    const float B0r = c1 * (bih[0] + bhh[0]);
    const float B0z = c1 * (bih[1] + bhh[1]);
    const float B0n = c2 *  bih[2];
    float wr[8], wz[8], wn[8];
    #pragma unroll
    for (int d = 0; d < 8; ++d) {
        wr[d] = c1 * Wih0[d];
        wz[d] = c1 * Wih0[8 + d];
        wn[d] = c2 * Wih0[16 + d];
    }

    // lane j of a group loads only step j's 32B of each chunk
    const float4* xpA = reinterpret_cast<const float4*>(x + (size_t)bA * T8) + (lane & 7) * 2;
    const float4* xpB = reinterpret_cast<const float4*>(x + (size_t)bB * T8) + (lane & 7) * 2;

    float4 LA0[2], LA1[2], LA2[2], LA3[2];   // chain A chunk buffers
    float4 LB0[2], LB1[2], LB2[2], LB3[2];   // chain B chunk buffers
    float  SrA0[8], SzA0[8], SnA0[8], SrA1[8], SzA1[8], SnA1[8];
    float  SrB0[8], SzB0[8], SnB0[8], SrB1[8], SzB1[8], SnB1[8];
    float  hA = 0.0f, hB = 0.0f;

    auto loadL = [&](const float4* xp, float4 (&L)[2], int c) {
        const int cc = (c < NCH) ? c : 0;    // clamp: harmless re-read
        const float4* p = xp + (size_t)cc * 16;
        L[0] = p[0];
        L[1] = p[1];
    };

    // distributed projection + group broadcast + base select (all off h-chain)
    auto prep = [&](const float4 (&L)[2],
                    float (&sr)[8], float (&sz)[8], float (&sn)[8]) {
        const float4 a  = L[0];
        const float4 b4 = L[1];
        float pr = B0r, pz = B0z, pn = B0n;
        pr = fmaf(a.x,  wr[0], pr); pr = fmaf(a.y,  wr[1], pr);
        pr = fmaf(a.z,  wr[2], pr); pr = fmaf(a.w,  wr[3], pr);
        pr = fmaf(b4.x, wr[4], pr); pr = fmaf(b4.y, wr[5], pr);
        pr = fmaf(b4.z, wr[6], pr); pr = fmaf(b4.w, wr[7], pr);
        pz = fmaf(a.x,  wz[0], pz); pz = fmaf(a.y,  wz[1], pz);
        pz = fmaf(a.z,  wz[2], pz); pz = fmaf(a.w,  wz[3], pz);
        pz = fmaf(b4.x, wz[4], pz); pz = fmaf(b4.y, wz[5], pz);
        pz = fmaf(b4.z, wz[6], pz); pz = fmaf(b4.w, wz[7], pz);
        pn = fmaf(a.x,  wn[0], pn); pn = fmaf(a.y,  wn[1], pn);
        pn = fmaf(a.z,  wn[2], pn); pn = fmaf(a.w,  wn[3], pn);
        pn = fmaf(b4.x, wn[4], pn); pn = fmaf(b4.y, wn[5], pn);
        pn = fmaf(b4.z, wn[6], pn); pn = fmaf(b4.w, wn[7], pn);

        const int ipr = __builtin_bit_cast(int, pr);
        const int ipz = __builtin_bit_cast(int, pz);
        const int ipn = __builtin_bit_cast(int, pn);

#define BCAST_STEP(S)                                                         \
        {                                                                     \
            const float qr = __builtin_bit_cast(float,                        \
                __builtin_amdgcn_ds_swizzle(ipr, ((S) << 5) | 0x18));         \
            const float qz = __builtin_bit_cast(float,                        \
                __builtin_amdgcn_ds_swizzle(ipz, ((S) << 5) | 0x18));         \
            const float qn = __builtin_bit_cast(float,                        \
                __builtin_amdgcn_ds_swizzle(ipn, ((S) << 5) | 0x18));         \
            sr[S] = lz ? qr : B1r;                                            \
            sz[S] = lz ? qz : B1z;                                            \
            sn[S] = lz ? qn : B1n;                                            \
        }
        BCAST_STEP(0) BCAST_STEP(1) BCAST_STEP(2) BCAST_STEP(3)
        BCAST_STEP(4) BCAST_STEP(5) BCAST_STEP(6) BCAST_STEP(7)
#undef BCAST_STEP
    };

    // two independent step bodies, interleaved for ILP
    auto step2 = [&](int i, float brA, float bzA, float bnA,
                            float brB, float bzB, float bnB, bool guard) {
        const float nbrA = dpp_shr1(hA);
        const float nbrB = dpp_shr1(hB);

        const float t1A = fmaf(whpr, hA, brA);
        const float t1B = fmaf(whpr, hB, brB);
        const float arA = fmaf(W1r, nbrA, t1A);
        const float arB = fmaf(W1r, nbrB, t1B);
        const float erA = __builtin_amdgcn_exp2f(arA);
        const float erB = __builtin_amdgcn_exp2f(arB);
        const float rA  = __builtin_amdgcn_rcpf(1.0f + erA);
        const float rB  = __builtin_amdgcn_rcpf(1.0f + erB);

        const float t2A = fmaf(whpz, hA, bzA);
        const float t2B = fmaf(whpz, hB, bzB);
        const float azA = fmaf(W1z, nbrA, t2A);
        const float azB = fmaf(W1z, nbrB, t2B);
        const float ezA = __builtin_amdgcn_exp2f(azA);
        const float ezB = __builtin_amdgcn_exp2f(azB);
        const float zA  = __builtin_amdgcn_rcpf(1.0f + ezA);
        const float zB  = __builtin_amdgcn_rcpf(1.0f + ezB);

        const float tnA  = fmaf(whpn, hA, bhpn);
        const float tnB  = fmaf(whpn, hB, bhpn);
        const float xnpA = fmaf(W1n, nbrA, bnA);
        const float xnpB = fmaf(W1n, nbrB, bnB);
        const float naA  = fmaf(rA, tnA, xnpA);
        const float naB  = fmaf(rB, tnB, xnpB);
        const float enA  = __builtin_amdgcn_exp2f(naA);
        const float enB  = __builtin_amdgcn_exp2f(naB);
        const float ddA  = __builtin_amdgcn_rcpf(1.0f + enA);
        const float ddB  = __builtin_amdgcn_rcpf(1.0f + enB);

        // hn = (2-2z)*dd + z*(h+1) - 1
        const float o2A = fmaf(-2.0f, zA, 2.0f);
        const float o2B = fmaf(-2.0f, zB, 2.0f);
        const float bsA = fmaf(zA, hA + 1.0f, -1.0f);
        const float bsB = fmaf(zB, hB + 1.0f, -1.0f);
        const float hnA = fmaf(o2A, ddA, bsA);
        const float hnB = fmaf(o2B, ddB, bsB);

        if (guard) {
            const bool ok = (unsigned)(i - l) < (unsigned)T_LEN;
            hA = ok ? hnA : hA;
            hB = ok ? hnB : hB;
        } else {
            hA = hnA;
            hB = hnB;
        }
    };

    auto runc2 = [&](const float (&srA)[8], const float (&szA)[8], const float (&snA)[8],
                     const float (&srB)[8], const float (&szB)[8], const float (&snB)[8],
                     int c, bool guard) {
        #pragma unroll
        for (int s = 0; s < 8; ++s)
            step2(c * 8 + s, srA[s], szA[s], snA[s], srB[s], szB[s], snB[s], guard);
    };

#define LOAD2(Lbuf, c)  { loadL(xpA, LA##Lbuf, (c)); loadL(xpB, LB##Lbuf, (c)); }
#define PREP2(Lbuf, Sb) { prep(LA##Lbuf, SrA##Sb, SzA##Sb, SnA##Sb); \
                          prep(LB##Lbuf, SrB##Sb, SzB##Sb, SnB##Sb); }
#define RUN2(Sb, c, gd) runc2(SrA##Sb, SzA##Sb, SnA##Sb, SrB##Sb, SzB##Sb, SnB##Sb, (c), (gd))

    // ---- software pipeline: load(c+3) | prep(c+1) | run(c) ----
    LOAD2(0, 0) LOAD2(1, 1) LOAD2(2, 2)
    PREP2(0, 0)

    LOAD2(3, 3) PREP2(1, 1) RUN2(0, 0, true);
    LOAD2(0, 4) PREP2(2, 0) RUN2(1, 1, false);
    LOAD2(1, 5) PREP2(3, 1) RUN2(0, 2, false);
    LOAD2(2, 6) PREP2(0, 0) RUN2(1, 3, false);

    #pragma unroll 1
    for (int q = 1; q < 64; ++q) {
        const int c0 = q * 4;
        LOAD2(3, c0 + 3) PREP2(1, 1) RUN2(0, c0,     false);
        LOAD2(0, c0 + 4) PREP2(2, 0) RUN2(1, c0 + 1, false);
        LOAD2(1, c0 + 5) PREP2(3, 1) RUN2(0, c0 + 2, false);
        LOAD2(2, c0 + 6) PREP2(0, 0) RUN2(1, c0 + 3, false);
    }

    // tail: 5 guarded steps, no x (layer 0 frozen; layers 1..5 finish)
    #pragma unroll
    for (int i = T_LEN; i < T_LEN + 5; ++i)
        step2(i, B1r, B1z, B1n, B1r, B1z, B1n, true);

    if (l == 5) {
        out[bA] = hA;    // layer-5 h frozen at t = T-1
        out[bB] = hB;
    }
}

extern "C" void kernel_launch(void* const* d_in, const int* in_sizes, int n_in,
                              void* d_out, int out_size, void* d_ws, size_t ws_size,
                              hipStream_t stream) {
    const float* x     = (const float*)d_in[0];
    const float* Wih0  = (const float*)d_in[1];
    const float* Wrest = (const float*)d_in[2];
    const float* Whh   = (const float*)d_in[3];
    const float* bih   = (const float*)d_in[4];
    const float* bhh   = (const float*)d_in[5];
    float* out = (float*)d_out;

    gru_scan<<<256, 64, 0, stream>>>(x, Wih0, Wrest, Whh, bih, bhh, out);
}

// Round 9
// 206.161 us; speedup vs baseline: 1.6984x; 1.6984x over previous
//
#include <hip/hip_runtime.h>

// GRU stack, hidden_size=1, 6 layers, B=4096, T=2048, D=8.
// One 8-lane group per batch element: lanes 0..5 = layers (skewed pipeline).
// Layer l at iteration i handles t = i - l; previous layer's h arrives via
// DPP row_shr:1 (row-crossing lanes 0,16,32,48 are all l==0 -> ignore nbr).
//
// Cost model from rounds 1/4/6: cy/step ~= 6.5*inst + 77 (chain floor).
// This round cuts instructions on the r6 base (202us):
//  - z-gate flipped: compute zbar=1-z directly (constants scaled by +log2e),
//    tail becomes hn = fma(zbar, fma(2,dd,-(1+h)), h)  (3 ops, shorter chain)
//  - packed-f32 pairs via ext_vector_type(2) for (t1,t2),(ar,az),(tn,xnp)
//    and prep's r/z dots -- compiler may emit v_pk_fma_f32; harmless if not.
// Multi-chain-per-wave is a dead end (r8): wall time = per-wave step latency,
// wave count is irrelevant (SIMDs idle either way).
//
// Gate math in exp2 form, constants pre-folded:
//   sigmoid(p) = rcp(1 + exp2(c1*p)),  c1 = -log2(e)   [r gate]
//   1-sigmoid(p) = rcp(1 + exp2(cz*p)), cz = +log2(e)  [zbar]
//   tanh(y)    = 2*rcp(1 + exp2(c2*y)) - 1,  c2 = -2*log2(e)

#define T_LEN 2048
#define T8    (T_LEN * 8)
#define NCH   256          // 8-step chunks

typedef __attribute__((ext_vector_type(2))) float v2f;

__device__ __forceinline__ float dpp_shr1(float v) {
    int i = __builtin_bit_cast(int, v);
    int r = __builtin_amdgcn_update_dpp(0, i, 0x111 /*row_shr:1*/, 0xF, 0xF, true);
    return __builtin_bit_cast(float, r);
}

__global__ __launch_bounds__(64)
__attribute__((amdgpu_waves_per_eu(1, 1)))
void gru_scan(const float* __restrict__ x,
              const float* __restrict__ Wih0,   // [3][8]
              const float* __restrict__ Wrest,  // [5][3]
              const float* __restrict__ Whh,    // [6][3]
              const float* __restrict__ bih,    // [6][3]
              const float* __restrict__ bhh,    // [6][3]
              float* __restrict__ out)          // [B]
{
    const int lane = threadIdx.x & 63;   // block = 1 wave
    const int l    = lane & 7;           // 0..5 layers; 6,7 proj-only helpers
    const int g    = lane >> 3;          // group (batch) within wave
    const int b    = blockIdx.x * 8 + g;

    const float c1 = -1.44269504088896340736f;   // -log2(e)  [r gate]
    const float cz =  1.44269504088896340736f;   // +log2(e)  [zbar gate]
    const float c2 = 2.0f * c1;                  // [n gate]

    const int  lidx = l < 6 ? l : 5;
    const bool lz   = (l == 0);
    const float m1  = lz ? 0.0f : 1.0f;

    // own-layer hidden constants
    const float whpr = c1 * Whh[lidx * 3 + 0];
    const float whpz = cz * Whh[lidx * 3 + 1];
    const float whpn = c2 * Whh[lidx * 3 + 2];
    const float bhpn = c2 * bhh[lidx * 3 + 2];
    const v2f  WH12 = {whpr, whpz};

    const int ir = lidx >= 1 ? lidx - 1 : 0;
    const float W1r = m1 * c1 * Wrest[ir * 3 + 0];
    const float W1z = m1 * cz * Wrest[ir * 3 + 1];
    const float W1n = m1 * c2 * Wrest[ir * 3 + 2];
    const v2f  W1rz = {W1r, W1z};
    const float B1r = c1 * (bih[lidx * 3 + 0] + bhh[lidx * 3 + 0]);
    const float B1z = cz * (bih[lidx * 3 + 1] + bhh[lidx * 3 + 1]);
    const float B1n = c2 *  bih[lidx * 3 + 2];
    const v2f  B1rz = {B1r, B1z};

    // layer-0 constants (uniform) for the distributed projection
    const float B0r = c1 * (bih[0] + bhh[0]);
    const float B0z = cz * (bih[1] + bhh[1]);
    const float B0n = c2 *  bih[2];
    v2f  wrz[8];
    float wn[8];
    #pragma unroll
    for (int d = 0; d < 8; ++d) {
        wrz[d] = (v2f){c1 * Wih0[d], cz * Wih0[8 + d]};
        wn[d]  = c2 * Wih0[16 + d];
    }

    // lane j of a group loads only step j's 32B of each chunk
    const float4* xp = reinterpret_cast<const float4*>(x + (size_t)b * T8) + (lane & 7) * 2;

    float4 L0[2], L1[2], L2[2], L3[2];   // chunk c -> L[c&3]
    v2f    Srz0[8], Srz1[8];             // chunk c -> S[c&1]
    float  Sn0[8],  Sn1[8];
    float  h = 0.0f;

    auto loadL = [&](float4 (&L)[2], int c) {
        const int cc = (c < NCH) ? c : 0;    // clamp: harmless re-read
        const float4* p = xp + (size_t)cc * 16;
        L[0] = p[0];
        L[1] = p[1];
    };

    // distributed projection + group broadcast + base select (all off h-chain)
    auto prep = [&](const float4 (&L)[2], v2f (&srz)[8], float (&sn)[8]) {
        const float4 a  = L[0];
        const float4 b4 = L[1];
        v2f   prz = {B0r, B0z};
        float pn  = B0n;
        prz = wrz[0] * (v2f){a.x,  a.x } + prz;  pn = fmaf(a.x,  wn[0], pn);
        prz = wrz[1] * (v2f){a.y,  a.y } + prz;  pn = fmaf(a.y,  wn[1], pn);
        prz = wrz[2] * (v2f){a.z,  a.z } + prz;  pn = fmaf(a.z,  wn[2], pn);
        prz = wrz[3] * (v2f){a.w,  a.w } + prz;  pn = fmaf(a.w,  wn[3], pn);
        prz = wrz[4] * (v2f){b4.x, b4.x} + prz;  pn = fmaf(b4.x, wn[4], pn);
        prz = wrz[5] * (v2f){b4.y, b4.y} + prz;  pn = fmaf(b4.y, wn[5], pn);
        prz = wrz[6] * (v2f){b4.z, b4.z} + prz;  pn = fmaf(b4.z, wn[6], pn);
        prz = wrz[7] * (v2f){b4.w, b4.w} + prz;  pn = fmaf(b4.w, wn[7], pn);

        const float prf = prz.x, pzf = prz.y;
        const int ipr = __builtin_bit_cast(int, prf);
        const int ipz = __builtin_bit_cast(int, pzf);
        const int ipn = __builtin_bit_cast(int, pn);

        // BitMode: src_lane = (lane & 0x18) | S -> broadcast step-S projection
#define BCAST_STEP(S)                                                         \
        {                                                                     \
            const float qr = __builtin_bit_cast(float,                        \
                __builtin_amdgcn_ds_swizzle(ipr, ((S) << 5) | 0x18));         \
            const float qz = __builtin_bit_cast(float,                        \
                __builtin_amdgcn_ds_swizzle(ipz, ((S) << 5) | 0x18));         \
            const float qn = __builtin_bit_cast(float,                        \
                __builtin_amdgcn_ds_swizzle(ipn, ((S) << 5) | 0x18));         \
            srz[S] = (v2f){lz ? qr : B1r, lz ? qz : B1z};                     \
            sn[S]  = lz ? qn : B1n;                                           \
        }
        BCAST_STEP(0) BCAST_STEP(1) BCAST_STEP(2) BCAST_STEP(3)
        BCAST_STEP(4) BCAST_STEP(5) BCAST_STEP(6) BCAST_STEP(7)
#undef BCAST_STEP
    };

    auto step1 = [&](int i, v2f brz, float bn, bool guard) {
        const float nbr = dpp_shr1(h);       // prev layer's h

        const v2f t12 = WH12 * (v2f){h, h} + brz;       // pk_fma
        const v2f arz = W1rz * (v2f){nbr, nbr} + t12;   // pk_fma
        const float er = __builtin_amdgcn_exp2f(arz.x);
        const float ez = __builtin_amdgcn_exp2f(arz.y);
        const float r  = __builtin_amdgcn_rcpf(1.0f + er);
        const float zb = __builtin_amdgcn_rcpf(1.0f + ez);   // zbar = 1-z

        const v2f tnx = (v2f){whpn, W1n} * (v2f){h, nbr} + (v2f){bhpn, bn};
        const float na = fmaf(r, tnx.x, tnx.y);
        const float en = __builtin_amdgcn_exp2f(na);
        const float dd = __builtin_amdgcn_rcpf(1.0f + en);

        // hn = h + zbar*(2dd - (1+h))
        const float p  = 1.0f + h;
        const float v  = fmaf(2.0f, dd, -p);
        const float hn = fmaf(zb, v, h);

        if (guard) {
            h = ((unsigned)(i - l) < (unsigned)T_LEN) ? hn : h;
        } else {
            h = hn;
        }
    };

    auto runc = [&](const v2f (&srz)[8], const float (&sn)[8], int c, bool guard) {
        #pragma unroll
        for (int s = 0; s < 8; ++s)
            step1(c * 8 + s, srz[s], sn[s], guard);
    };

    // ---- software pipeline: load(c+3) | prep(c+1) | run(c) ----
    loadL(L0, 0); loadL(L1, 1); loadL(L2, 2);
    prep(L0, Srz0, Sn0);

    loadL(L3, 3); prep(L1, Srz1, Sn1); runc(Srz0, Sn0, 0, true);
    loadL(L0, 4); prep(L2, Srz0, Sn0); runc(Srz1, Sn1, 1, false);
    loadL(L1, 5); prep(L3, Srz1, Sn1); runc(Srz0, Sn0, 2, false);
    loadL(L2, 6); prep(L0, Srz0, Sn0); runc(Srz1, Sn1, 3, false);

    #pragma unroll 1
    for (int q = 1; q < 64; ++q) {
        const int c0 = q * 4;
        loadL(L3, c0 + 3); prep(L1, Srz1, Sn1); runc(Srz0, Sn0, c0,     false);
        loadL(L0, c0 + 4); prep(L2, Srz0, Sn0); runc(Srz1, Sn1, c0 + 1, false);
        loadL(L1, c0 + 5); prep(L3, Srz1, Sn1); runc(Srz0, Sn0, c0 + 2, false);
        loadL(L2, c0 + 6); prep(L0, Srz0, Sn0); runc(Srz1, Sn1, c0 + 3, false);
    }

    // tail: 5 guarded steps, no x (layer 0 frozen; layers 1..5 finish)
    #pragma unroll
    for (int i = T_LEN; i < T_LEN + 5; ++i) step1(i, B1rz, B1n, true);

    if (l == 5) out[b] = h;          // layer-5 h frozen at t = T-1
}

extern "C" void kernel_launch(void* const* d_in, const int* in_sizes, int n_in,
                              void* d_out, int out_size, void* d_ws, size_t ws_size,
                              hipStream_t stream) {
    const float* x     = (const float*)d_in[0];
    const float* Wih0  = (const float*)d_in[1];
    const float* Wrest = (const float*)d_in[2];
    const float* Whh   = (const float*)d_in[3];
    const float* bih   = (const float*)d_in[4];
    const float* bhh   = (const float*)d_in[5];
    float* out = (float*)d_out;

    gru_scan<<<512, 64, 0, stream>>>(x, Wih0, Wrest, Whh, bih, bhh, out);
}

// Round 10
// 198.516 us; speedup vs baseline: 1.7639x; 1.0385x over previous
//
#include <hip/hip_runtime.h>

// GRU stack, hidden_size=1, 6 layers, B=4096, T=2048, D=8.
// One 8-lane group per batch element: lanes 0..5 = layers (skewed pipeline).
// Layer l at iteration i handles t = i - l; prev layer's h via DPP row_shr:1.
//
// THIS ROUND:
//  (1) merged rcp: hn = h + R*((1-h) - (1+h)*en), R = rcp((1+en)(1+ez))
//      -- one rcp for z+n gates (5 trans/step instead of 6), chain-neutral.
//  (2) full source-level software pipeline: the off-chain work (dots for
//      chunk c+2, swizzle+select broadcast for chunk c+1) is sliced PER STEP
//      between the chain ops, so the in-order issue can fill chain stalls.
//      Pipeline: dots(X) during run(X-2); swz+sel(X) during run(X-1);
//      S consumed at run(X). Loads 4 chunks ahead.
//
// Gate math in exp2 form, constants pre-folded:
//   sigmoid(p) = rcp(1 + exp2(c1*p)),  c1 = -log2(e)   [r gate]
//   1-sigmoid(p) = rcp(1 + exp2(cz*p)), cz = +log2(e)  [zbar]
//   tanh(y)    = 2*rcp(1 + exp2(c2*y)) - 1,  c2 = -2*log2(e)

#define T_LEN 2048
#define T8    (T_LEN * 8)
#define NCH   256          // 8-step chunks

typedef __attribute__((ext_vector_type(2))) float v2f;

__device__ __forceinline__ float dpp_shr1(float v) {
    int i = __builtin_bit_cast(int, v);
    int r = __builtin_amdgcn_update_dpp(0, i, 0x111 /*row_shr:1*/, 0xF, 0xF, true);
    return __builtin_bit_cast(float, r);
}

__global__ __launch_bounds__(64)
__attribute__((amdgpu_waves_per_eu(1, 1)))
void gru_scan(const float* __restrict__ x,
              const float* __restrict__ Wih0,   // [3][8]
              const float* __restrict__ Wrest,  // [5][3]
              const float* __restrict__ Whh,    // [6][3]
              const float* __restrict__ bih,    // [6][3]
              const float* __restrict__ bhh,    // [6][3]
              float* __restrict__ out)          // [B]
{
    const int lane = threadIdx.x & 63;   // block = 1 wave
    const int l    = lane & 7;           // 0..5 layers; 6,7 proj helpers
    const int g    = lane >> 3;          // group (batch) within wave
    const int b    = blockIdx.x * 8 + g;

    const float c1 = -1.44269504088896340736f;   // -log2(e)  [r gate]
    const float cz =  1.44269504088896340736f;   // +log2(e)  [zbar gate]
    const float c2 = 2.0f * c1;                  // [n gate]

    const int  lidx = l < 6 ? l : 5;
    const bool lz   = (l == 0);
    const float m1  = lz ? 0.0f : 1.0f;

    const float whpr = c1 * Whh[lidx * 3 + 0];
    const float whpz = cz * Whh[lidx * 3 + 1];
    const float whpn = c2 * Whh[lidx * 3 + 2];
    const float bhpn = c2 * bhh[lidx * 3 + 2];
    const v2f  WH12 = {whpr, whpz};

    const int ir = lidx >= 1 ? lidx - 1 : 0;
    const float W1r = m1 * c1 * Wrest[ir * 3 + 0];
    const float W1z = m1 * cz * Wrest[ir * 3 + 1];
    const float W1n = m1 * c2 * Wrest[ir * 3 + 2];
    const v2f  W1rz = {W1r, W1z};
    const float B1r = c1 * (bih[lidx * 3 + 0] + bhh[lidx * 3 + 0]);
    const float B1z = cz * (bih[lidx * 3 + 1] + bhh[lidx * 3 + 1]);
    const float B1n = c2 *  bih[lidx * 3 + 2];
    const v2f  B1rz = {B1r, B1z};

    // layer-0 projection constants (uniform)
    const v2f  B0rz = {c1 * (bih[0] + bhh[0]), cz * (bih[1] + bhh[1])};
    const float B0n = c2 * bih[2];
    v2f  wrz[8];
    float wn[8];
    #pragma unroll
    for (int d = 0; d < 8; ++d) {
        wrz[d] = (v2f){c1 * Wih0[d], cz * Wih0[8 + d]};
        wn[d]  = c2 * Wih0[16 + d];
    }

    // lane j of a group loads only step j's 32B of each chunk
    const float4* xp = reinterpret_cast<const float4*>(x + (size_t)b * T8) + (lane & 7) * 2;

    // L buffers: chunk c -> slot c&3 (each 2 x float4)
    float4 L0a, L0b, L1a, L1b, L2a, L2b, L3a, L3b;
    // S buffers: chunk c -> (c even ? SA : SB)
    v2f   SrzA[8], SrzB[8];
    float SnA[8],  SnB[8];
    // dot accumulators: chunk X -> (X even ? A : B)
    v2f   PRZA, PRZB;
    float PNA,  PNB;
    float h = 0.0f;

#define LOADL(A, B, C)                                                        \
    { const int cc_ = ((C) < NCH) ? (C) : 0;                                  \
      const float4* p_ = xp + (size_t)cc_ * 16;                               \
      A = p_[0]; B = p_[1]; }

#define GETF(S, A, B) ((S)==0?(A).x:(S)==1?(A).y:(S)==2?(A).z:(S)==3?(A).w:  \
                       (S)==4?(B).x:(S)==5?(B).y:(S)==6?(B).z:(B).w)

    // dot slice S of a chunk: one pk_fma + one fma (S==0 initializes)
#define DOT_SLICE(S, LA, LB, PRZ, PN)                                         \
    { const float xv_ = GETF(S, LA, LB);                                      \
      if ((S) == 0) { PRZ = wrz[0] * (v2f){xv_, xv_} + B0rz;                  \
                      PN  = fmaf(xv_, wn[0], B0n); }                          \
      else          { PRZ = wrz[S] * (v2f){xv_, xv_} + PRZ;                   \
                      PN  = fmaf(xv_, wn[S], PN); } }

    // broadcast step S's projection (from lane grp|S) + select vs B1
#define SWZ_SEL(S, PRZ, PN, SRZ, SN)                                          \
    { const int ipr_ = __builtin_bit_cast(int, (PRZ).x);                      \
      const int ipz_ = __builtin_bit_cast(int, (PRZ).y);                      \
      const int ipn_ = __builtin_bit_cast(int, (PN));                         \
      const float qr_ = __builtin_bit_cast(float,                             \
          __builtin_amdgcn_ds_swizzle(ipr_, ((S) << 5) | 0x18));              \
      const float qz_ = __builtin_bit_cast(float,                             \
          __builtin_amdgcn_ds_swizzle(ipz_, ((S) << 5) | 0x18));              \
      const float qn_ = __builtin_bit_cast(float,                             \
          __builtin_amdgcn_ds_swizzle(ipn_, ((S) << 5) | 0x18));              \
      SRZ[S] = (v2f){lz ? qr_ : B1r, lz ? qz_ : B1z};                         \
      SN[S]  = lz ? qn_ : B1n; }

    auto step1 = [&](int i, v2f brz, float bn, bool guard) {
        const float nbr = dpp_shr1(h);

        const v2f t12 = WH12 * (v2f){h, h} + brz;
        const v2f arz = W1rz * (v2f){nbr, nbr} + t12;
        const float er = __builtin_amdgcn_exp2f(arz.x);
        const float ez = __builtin_amdgcn_exp2f(arz.y);
        const float r  = __builtin_amdgcn_rcpf(1.0f + er);
        const float pz1 = 1.0f + ez;

        const v2f tnx = (v2f){whpn, W1n} * (v2f){h, nbr} + (v2f){bhpn, bn};
        const float na = fmaf(r, tnx.x, tnx.y);
        const float en = __builtin_amdgcn_exp2f(na);
        const float pn1 = 1.0f + en;

        const float P  = pn1 * pz1;
        const float R  = __builtin_amdgcn_rcpf(P);     // merged z+n rcp
        const float hp1 = h + 1.0f;
        const float hm1 = 1.0f - h;
        const float q  = fmaf(-hp1, en, hm1);
        const float hn = fmaf(R, q, h);                // h + R*q

        if (guard) {
            h = ((unsigned)(i - l) < (unsigned)T_LEN) ? hn : h;
        } else {
            h = hn;
        }
    };

    // one fused step: chain step + dot slice (chunk c+2) + swz slice (chunk c+1)
#define STEP_F(S, C, SRZr, SNr, PRZr, PNr, SRZw, SNw, PRZw, PNw, LnA, LnB, GD)\
    { step1((C) * 8 + (S), SRZr[S], SNr[S], GD);                              \
      DOT_SLICE(S, LnA, LnB, PRZw, PNw)                                       \
      SWZ_SEL(S, PRZr, PNr, SRZw, SNw) }

    // run chunk C: consume SRZr/SNr; build S(c+1) from acc(c+1)=PRZr/PNr;
    // accumulate acc(c+2)=PRZw/PNw from L(c+2)=Ln*; load chunk C4 into Ll*.
#define RUN_CHUNK(C, SRZr, SNr, SRZw, SNw, PRZr, PNr, PRZw, PNw,              \
                  LnA, LnB, LlA, LlB, C4, GD)                                 \
    { LOADL(LlA, LlB, C4)                                                     \
      STEP_F(0, C, SRZr, SNr, PRZr, PNr, SRZw, SNw, PRZw, PNw, LnA, LnB, GD)  \
      STEP_F(1, C, SRZr, SNr, PRZr, PNr, SRZw, SNw, PRZw, PNw, LnA, LnB, GD)  \
      STEP_F(2, C, SRZr, SNr, PRZr, PNr, SRZw, SNw, PRZw, PNw, LnA, LnB, GD)  \
      STEP_F(3, C, SRZr, SNr, PRZr, PNr, SRZw, SNw, PRZw, PNw, LnA, LnB, GD)  \
      STEP_F(4, C, SRZr, SNr, PRZr, PNr, SRZw, SNw, PRZw, PNw, LnA, LnB, GD)  \
      STEP_F(5, C, SRZr, SNr, PRZr, PNr, SRZw, SNw, PRZw, PNw, LnA, LnB, GD)  \
      STEP_F(6, C, SRZr, SNr, PRZr, PNr, SRZw, SNw, PRZw, PNw, LnA, LnB, GD)  \
      STEP_F(7, C, SRZr, SNr, PRZr, PNr, SRZw, SNw, PRZw, PNw, LnA, LnB, GD) }

    // ---- prologue: chunks 0..3 resident; dots(0),dots(1); swz(0) ----
    LOADL(L0a, L0b, 0) LOADL(L1a, L1b, 1) LOADL(L2a, L2b, 2) LOADL(L3a, L3b, 3)

    DOT_SLICE(0, L0a, L0b, PRZA, PNA) DOT_SLICE(1, L0a, L0b, PRZA, PNA)
    DOT_SLICE(2, L0a, L0b, PRZA, PNA) DOT_SLICE(3, L0a, L0b, PRZA, PNA)
    DOT_SLICE(4, L0a, L0b, PRZA, PNA) DOT_SLICE(5, L0a, L0b, PRZA, PNA)
    DOT_SLICE(6, L0a, L0b, PRZA, PNA) DOT_SLICE(7, L0a, L0b, PRZA, PNA)

    DOT_SLICE(0, L1a, L1b, PRZB, PNB) DOT_SLICE(1, L1a, L1b, PRZB, PNB)
    DOT_SLICE(2, L1a, L1b, PRZB, PNB) DOT_SLICE(3, L1a, L1b, PRZB, PNB)
    DOT_SLICE(4, L1a, L1b, PRZB, PNB) DOT_SLICE(5, L1a, L1b, PRZB, PNB)
    DOT_SLICE(6, L1a, L1b, PRZB, PNB) DOT_SLICE(7, L1a, L1b, PRZB, PNB)

    SWZ_SEL(0, PRZA, PNA, SrzA, SnA) SWZ_SEL(1, PRZA, PNA, SrzA, SnA)
    SWZ_SEL(2, PRZA, PNA, SrzA, SnA) SWZ_SEL(3, PRZA, PNA, SrzA, SnA)
    SWZ_SEL(4, PRZA, PNA, SrzA, SnA) SWZ_SEL(5, PRZA, PNA, SrzA, SnA)
    SWZ_SEL(6, PRZA, PNA, SrzA, SnA) SWZ_SEL(7, PRZA, PNA, SrzA, SnA)

    // ---- chunk 0 (guarded) .. chunk 3 ----
    RUN_CHUNK(0, SrzA, SnA, SrzB, SnB, PRZB, PNB, PRZA, PNA, L2a, L2b, L0a, L0b, 4, true)
    RUN_CHUNK(1, SrzB, SnB, SrzA, SnA, PRZA, PNA, PRZB, PNB, L3a, L3b, L1a, L1b, 5, false)
    RUN_CHUNK(2, SrzA, SnA, SrzB, SnB, PRZB, PNB, PRZA, PNA, L0a, L0b, L2a, L2b, 6, false)
    RUN_CHUNK(3, SrzB, SnB, SrzA, SnA, PRZA, PNA, PRZB, PNB, L1a, L1b, L3a, L3b, 7, false)

    #pragma unroll 1
    for (int q = 1; q < 64; ++q) {
        const int c0 = q * 4;
        RUN_CHUNK(c0 + 0, SrzA, SnA, SrzB, SnB, PRZB, PNB, PRZA, PNA, L2a, L2b, L0a, L0b, c0 + 4, false)
        RUN_CHUNK(c0 + 1, SrzB, SnB, SrzA, SnA, PRZA, PNA, PRZB, PNB, L3a, L3b, L1a, L1b, c0 + 5, false)
        RUN_CHUNK(c0 + 2, SrzA, SnA, SrzB, SnB, PRZB, PNB, PRZA, PNA, L0a, L0b, L2a, L2b, c0 + 6, false)
        RUN_CHUNK(c0 + 3, SrzB, SnB, SrzA, SnA, PRZA, PNA, PRZB, PNB, L1a, L1b, L3a, L3b, c0 + 7, false)
    }

    // tail: 5 guarded steps, no x (layer 0 frozen; layers 1..5 finish)
    #pragma unroll
    for (int i = T_LEN; i < T_LEN + 5; ++i) step1(i, B1rz, B1n, true);

    if (l == 5) out[b] = h;          // layer-5 h frozen at t = T-1
}

extern "C" void kernel_launch(void* const* d_in, const int* in_sizes, int n_in,
                              void* d_out, int out_size, void* d_ws, size_t ws_size,
                              hipStream_t stream) {
    const float* x     = (const float*)d_in[0];
    const float* Wih0  = (const float*)d_in[1];
    const float* Wrest = (const float*)d_in[2];
    const float* Whh   = (const float*)d_in[3];
    const float* bih   = (const float*)d_in[4];
    const float* bhh   = (const float*)d_in[5];
    float* out = (float*)d_out;

    gru_scan<<<512, 64, 0, stream>>>(x, Wih0, Wrest, Whh, bih, bhh, out);
}

// Round 11
// 152.276 us; speedup vs baseline: 2.2995x; 1.3037x over previous
//
#include <hip/hip_runtime.h>

// GRU stack, hidden_size=1, 6 layers, B=4096, T=2048, D=8.
// One 8-lane group per batch element: lanes 0..5 = layers (skewed pipeline).
// Layer l at iteration i handles t = i - l; prev layer's h via DPP row_shr:1.
//
// THIS ROUND: replace the per-step 3x ds_swizzle projection broadcast (LDS
// pipe -> ~40cy lgkmcnt wait each, the dominant per-step stall per r9/r10
// flatness) with a DPP CONVEYOR: lane j computes proj(step j) (distributed
// dots, unchanged); the three proj values ride a register "belt" shifted one
// lane toward lane 0 each step (row_shl:1) so lane 8q holds proj(s) exactly
// at step s. Cross-group/row-boundary garbage only enters belt slots that
// are never consumed (only lane 8q reads the belt). NO LDS ops remain.
//
// Gate math in exp2 form, constants pre-folded:
//   sigmoid(p) = rcp(1 + exp2(c1*p)),  c1 = -log2(e)   [r gate]
//   1-sigmoid(p) = rcp(1 + exp2(cz*p)), cz = +log2(e)  [zbar]
//   tanh(y)    = 2*rcp(1 + exp2(c2*y)) - 1,  c2 = -2*log2(e)
//   merged rcp: hn = h + R*((1-h) - (1+h)*en), R = rcp((1+en)(1+ez))

#define T_LEN 2048
#define T8    (T_LEN * 8)
#define NCH   256          // 8-step chunks

typedef __attribute__((ext_vector_type(2))) float v2f;

__device__ __forceinline__ float dpp_shr1(float v) {   // lane i <- lane i-1
    int i = __builtin_bit_cast(int, v);
    int r = __builtin_amdgcn_update_dpp(0, i, 0x111, 0xF, 0xF, true);
    return __builtin_bit_cast(float, r);
}
__device__ __forceinline__ float dpp_shl1(float v) {   // lane i <- lane i+1
    int i = __builtin_bit_cast(int, v);
    int r = __builtin_amdgcn_update_dpp(0, i, 0x101, 0xF, 0xF, true);
    return __builtin_bit_cast(float, r);
}

__global__ __launch_bounds__(64)
__attribute__((amdgpu_waves_per_eu(1, 1)))
void gru_scan(const float* __restrict__ x,
              const float* __restrict__ Wih0,   // [3][8]
              const float* __restrict__ Wrest,  // [5][3]
              const float* __restrict__ Whh,    // [6][3]
              const float* __restrict__ bih,    // [6][3]
              const float* __restrict__ bhh,    // [6][3]
              float* __restrict__ out)          // [B]
{
    const int lane = threadIdx.x & 63;   // block = 1 wave
    const int l    = lane & 7;           // 0..5 layers; 6,7 proj helpers
    const int g    = lane >> 3;          // group (batch) within wave
    const int b    = blockIdx.x * 8 + g;

    const float c1 = -1.44269504088896340736f;   // -log2(e)  [r gate]
    const float cz =  1.44269504088896340736f;   // +log2(e)  [zbar gate]
    const float c2 = 2.0f * c1;                  // [n gate]

    const int  lidx = l < 6 ? l : 5;
    const bool lz   = (l == 0);
    const float m1  = lz ? 0.0f : 1.0f;

    const float whpr = c1 * Whh[lidx * 3 + 0];
    const float whpz = cz * Whh[lidx * 3 + 1];
    const float whpn = c2 * Whh[lidx * 3 + 2];
    const float bhpn = c2 * bhh[lidx * 3 + 2];
    const v2f  WH12 = {whpr, whpz};

    const int ir = lidx >= 1 ? lidx - 1 : 0;
    const float W1r = m1 * c1 * Wrest[ir * 3 + 0];
    const float W1z = m1 * cz * Wrest[ir * 3 + 1];
    const float W1n = m1 * c2 * Wrest[ir * 3 + 2];
    const v2f  W1rz = {W1r, W1z};
    const float B1r = c1 * (bih[lidx * 3 + 0] + bhh[lidx * 3 + 0]);
    const float B1z = cz * (bih[lidx * 3 + 1] + bhh[lidx * 3 + 1]);
    const float B1n = c2 *  bih[lidx * 3 + 2];
    const v2f  B1rz = {B1r, B1z};

    // layer-0 projection constants (uniform)
    const v2f  B0rz = {c1 * (bih[0] + bhh[0]), cz * (bih[1] + bhh[1])};
    const float B0n = c2 * bih[2];
    v2f  wrz[8];
    float wn[8];
    #pragma unroll
    for (int d = 0; d < 8; ++d) {
        wrz[d] = (v2f){c1 * Wih0[d], cz * Wih0[8 + d]};
        wn[d]  = c2 * Wih0[16 + d];
    }

    // lane j of a group loads only step j's 32B of each chunk
    const float4* xp = reinterpret_cast<const float4*>(x + (size_t)b * T8) + (lane & 7) * 2;

    // L buffers: chunk c -> slot c&3
    float4 L0a, L0b, L1a, L1b, L2a, L2b, L3a, L3b;
    // dot accumulator (being built for the NEXT chunk)
    v2f   PRZ;
    float PN;
    // the belt: proj values riding toward lane 0
    float belt_r, belt_z, belt_n;
    float h = 0.0f;

#define LOADL(A, B, C)                                                        \
    { const int cc_ = ((C) < NCH) ? (C) : 0;                                  \
      const float4* p_ = xp + (size_t)cc_ * 16;                               \
      A = p_[0]; B = p_[1]; }

#define GETF(S, A, B) ((S)==0?(A).x:(S)==1?(A).y:(S)==2?(A).z:(S)==3?(A).w:  \
                       (S)==4?(B).x:(S)==5?(B).y:(S)==6?(B).z:(B).w)

    // dot slice S (dimension S) of the next chunk: pk_fma + fma
#define DOT_SLICE(S, LA, LB)                                                  \
    { const float xv_ = GETF(S, LA, LB);                                      \
      if ((S) == 0) { PRZ = wrz[0] * (v2f){xv_, xv_} + B0rz;                  \
                      PN  = fmaf(xv_, wn[0], B0n); }                          \
      else          { PRZ = wrz[S] * (v2f){xv_, xv_} + PRZ;                   \
                      PN  = fmaf(xv_, wn[S], PN); } }

    auto step1 = [&](int i, v2f brz, float bn, bool guard) {
        const float nbr = dpp_shr1(h);

        const v2f t12 = WH12 * (v2f){h, h} + brz;
        const v2f arz = W1rz * (v2f){nbr, nbr} + t12;
        const float er = __builtin_amdgcn_exp2f(arz.x);
        const float ez = __builtin_amdgcn_exp2f(arz.y);
        const float r  = __builtin_amdgcn_rcpf(1.0f + er);
        const float pz1 = 1.0f + ez;

        const v2f tnx = (v2f){whpn, W1n} * (v2f){h, nbr} + (v2f){bhpn, bn};
        const float na = fmaf(r, tnx.x, tnx.y);
        const float en = __builtin_amdgcn_exp2f(na);
        const float pn1 = 1.0f + en;

        const float P  = pn1 * pz1;
        const float R  = __builtin_amdgcn_rcpf(P);     // merged z+n rcp
        const float hp1 = h + 1.0f;
        const float hm1 = 1.0f - h;
        const float q  = fmaf(-hp1, en, hm1);
        const float hn = fmaf(R, q, h);                // h + R*q

        if (guard) {
            h = ((unsigned)(i - l) < (unsigned)T_LEN) ? hn : h;
        } else {
            h = hn;
        }
    };

    // one fused step: belt-select -> chain; dot slice for next chunk; belt shift
#define STEP_B(S, C, LNa, LNb, GD)                                            \
    { const v2f  brz_ = lz ? (v2f){belt_r, belt_z} : B1rz;                    \
      const float bn_ = lz ? belt_n : B1n;                                    \
      step1((C) * 8 + (S), brz_, bn_, GD);                                    \
      DOT_SLICE(S, LNa, LNb)                                                  \
      belt_r = dpp_shl1(belt_r);                                              \
      belt_z = dpp_shl1(belt_z);                                              \
      belt_n = dpp_shl1(belt_n); }

    // run chunk C: belt holds proj(C); dots build proj(C+1) from LN*;
    // load chunk C4 into Ll*; refill belt from dots at the end.
#define RUN_CHUNK(C, LNa, LNb, LlA, LlB, C4, GD)                              \
    { LOADL(LlA, LlB, C4)                                                     \
      STEP_B(0, C, LNa, LNb, GD) STEP_B(1, C, LNa, LNb, GD)                   \
      STEP_B(2, C, LNa, LNb, GD) STEP_B(3, C, LNa, LNb, GD)                   \
      STEP_B(4, C, LNa, LNb, GD) STEP_B(5, C, LNa, LNb, GD)                   \
      STEP_B(6, C, LNa, LNb, GD) STEP_B(7, C, LNa, LNb, GD)                   \
      belt_r = PRZ.x; belt_z = PRZ.y; belt_n = PN; }

    // ---- prologue: chunks 0..2 resident; dots(0) -> belt ----
    LOADL(L0a, L0b, 0) LOADL(L1a, L1b, 1) LOADL(L2a, L2b, 2)

    DOT_SLICE(0, L0a, L0b) DOT_SLICE(1, L0a, L0b)
    DOT_SLICE(2, L0a, L0b) DOT_SLICE(3, L0a, L0b)
    DOT_SLICE(4, L0a, L0b) DOT_SLICE(5, L0a, L0b)
    DOT_SLICE(6, L0a, L0b) DOT_SLICE(7, L0a, L0b)
    belt_r = PRZ.x; belt_z = PRZ.y; belt_n = PN;

    // ---- chunk 0 (guarded) .. chunk 3 ----
    RUN_CHUNK(0, L1a, L1b, L3a, L3b, 3, true)
    RUN_CHUNK(1, L2a, L2b, L0a, L0b, 4, false)
    RUN_CHUNK(2, L3a, L3b, L1a, L1b, 5, false)
    RUN_CHUNK(3, L0a, L0b, L2a, L2b, 6, false)

    #pragma unroll 1
    for (int q = 1; q < 64; ++q) {
        const int c0 = q * 4;
        RUN_CHUNK(c0 + 0, L1a, L1b, L3a, L3b, c0 + 3, false)
        RUN_CHUNK(c0 + 1, L2a, L2b, L0a, L0b, c0 + 4, false)
        RUN_CHUNK(c0 + 2, L3a, L3b, L1a, L1b, c0 + 5, false)
        RUN_CHUNK(c0 + 3, L0a, L0b, L2a, L2b, c0 + 6, false)
    }

    // tail: 5 guarded steps, no x (layer 0 frozen; layers 1..5 finish)
    #pragma unroll
    for (int i = T_LEN; i < T_LEN + 5; ++i) step1(i, B1rz, B1n, true);

    if (l == 5) out[b] = h;          // layer-5 h frozen at t = T-1
}

extern "C" void kernel_launch(void* const* d_in, const int* in_sizes, int n_in,
                              void* d_out, int out_size, void* d_ws, size_t ws_size,
                              hipStream_t stream) {
    const float* x     = (const float*)d_in[0];
    const float* Wih0  = (const float*)d_in[1];
    const float* Wrest = (const float*)d_in[2];
    const float* Whh   = (const float*)d_in[3];
    const float* bih   = (const float*)d_in[4];
    const float* bhh   = (const float*)d_in[5];
    float* out = (float*)d_out;

    gru_scan<<<512, 64, 0, stream>>>(x, Wih0, Wrest, Whh, bih, bhh, out);
}

// Round 12
// 148.454 us; speedup vs baseline: 2.3587x; 1.0257x over previous
//
#include <hip/hip_runtime.h>

// GRU stack, hidden_size=1, 6 layers, B=4096, T=2048, D=8.
// One 8-lane group per batch element: lanes 0..5 = layers (skewed pipeline).
// Layer l at iteration i handles t = i - l; prev layer's h via DPP row_shr:1.
//
// THIS ROUND: remove the serial DPP belt (r11) -- per-chunk STATIC row_shl:s
// reads from stationary proj registers, preselected into S[8] arrays one
// slot per step, one chunk ahead. No DPP-to-DPP serial chains, no VALU->DPP
// RAW hazards (sources written a chunk earlier), and every non-chain op is
// independent -> scheduler can fill trans-latency stalls. Chain trim:
// P = fma(en, pz1, pz1) = (1+en)(1+ez) with pz1 off-chain.
//
// Pipeline: load(c+4) | dots(c+2) | presel(c+1) | run(c), all register-resident.
//
// Gate math in exp2 form, constants pre-folded:
//   sigmoid(p) = rcp(1 + exp2(c1*p)),  c1 = -log2(e)   [r gate]
//   1-sigmoid(p) = rcp(1 + exp2(cz*p)), cz = +log2(e)  [zbar]
//   tanh(y)    = 2*rcp(1 + exp2(c2*y)) - 1,  c2 = -2*log2(e)
//   merged rcp: hn = h + R*((1-h) - (1+h)*en), R = rcp((1+en)(1+ez))

#define T_LEN 2048
#define T8    (T_LEN * 8)
#define NCH   256          // 8-step chunks

typedef __attribute__((ext_vector_type(2))) float v2f;

__device__ __forceinline__ float dpp_shr1(float v) {   // lane i <- lane i-1
    int i = __builtin_bit_cast(int, v);
    int r = __builtin_amdgcn_update_dpp(0, i, 0x111, 0xF, 0xF, true);
    return __builtin_bit_cast(float, r);
}

// static row_shl:S (lane i <- lane i+S), S must be a literal 1..7
#define DPPSHL(S, v) __builtin_bit_cast(float,                                \
    __builtin_amdgcn_update_dpp(0, __builtin_bit_cast(int, (v)),              \
                                0x100 | ((S) == 0 ? 1 : (S)), 0xF, 0xF, true))
#define DPPSHLX(S, v) ((S) == 0 ? (v) : DPPSHL(S, v))

__global__ __launch_bounds__(64)
__attribute__((amdgpu_waves_per_eu(1, 1)))
void gru_scan(const float* __restrict__ x,
              const float* __restrict__ Wih0,   // [3][8]
              const float* __restrict__ Wrest,  // [5][3]
              const float* __restrict__ Whh,    // [6][3]
              const float* __restrict__ bih,    // [6][3]
              const float* __restrict__ bhh,    // [6][3]
              float* __restrict__ out)          // [B]
{
    const int lane = threadIdx.x & 63;   // block = 1 wave
    const int l    = lane & 7;           // 0..5 layers; 6,7 proj helpers
    const int g    = lane >> 3;          // group (batch) within wave
    const int b    = blockIdx.x * 8 + g;

    const float c1 = -1.44269504088896340736f;   // -log2(e)  [r gate]
    const float cz =  1.44269504088896340736f;   // +log2(e)  [zbar gate]
    const float c2 = 2.0f * c1;                  // [n gate]

    const int  lidx = l < 6 ? l : 5;
    const bool lz   = (l == 0);
    const float m1  = lz ? 0.0f : 1.0f;

    const float whpr = c1 * Whh[lidx * 3 + 0];
    const float whpz = cz * Whh[lidx * 3 + 1];
    const float whpn = c2 * Whh[lidx * 3 + 2];
    const float bhpn = c2 * bhh[lidx * 3 + 2];
    const v2f  WH12 = {whpr, whpz};

    const int ir = lidx >= 1 ? lidx - 1 : 0;
    const float W1r = m1 * c1 * Wrest[ir * 3 + 0];
    const float W1z = m1 * cz * Wrest[ir * 3 + 1];
    const float W1n = m1 * c2 * Wrest[ir * 3 + 2];
    const v2f  W1rz = {W1r, W1z};
    const float B1r = c1 * (bih[lidx * 3 + 0] + bhh[lidx * 3 + 0]);
    const float B1z = cz * (bih[lidx * 3 + 1] + bhh[lidx * 3 + 1]);
    const float B1n = c2 *  bih[lidx * 3 + 2];
    const v2f  B1rz = {B1r, B1z};

    // layer-0 projection constants (uniform)
    const v2f  B0rz = {c1 * (bih[0] + bhh[0]), cz * (bih[1] + bhh[1])};
    const float B0n = c2 * bih[2];
    v2f  wrz[8];
    float wn[8];
    #pragma unroll
    for (int d = 0; d < 8; ++d) {
        wrz[d] = (v2f){c1 * Wih0[d], cz * Wih0[8 + d]};
        wn[d]  = c2 * Wih0[16 + d];
    }

    // lane j of a group loads only step j's 32B of each chunk
    const float4* xp = reinterpret_cast<const float4*>(x + (size_t)b * T8) + (lane & 7) * 2;

    // L buffers: chunk c -> slot c&3
    float4 L0a, L0b, L1a, L1b, L2a, L2b, L3a, L3b;
    // dot accumulators: chunk c -> PZ[c&1]
    v2f   PZArz, PZBrz;
    float PZAn,  PZBn;
    // preselected per-step gate bases: chunk c -> S[c&1]
    v2f   SrzA[8], SrzB[8];
    float SnA[8],  SnB[8];
    float h = 0.0f;

#define LOADL(A, B, C)                                                        \
    { const int cc_ = ((C) < NCH) ? (C) : 0;                                  \
      const float4* p_ = xp + (size_t)cc_ * 16;                               \
      A = p_[0]; B = p_[1]; }

#define GETF(S, A, B) ((S)==0?(A).x:(S)==1?(A).y:(S)==2?(A).z:(S)==3?(A).w:  \
                       (S)==4?(B).x:(S)==5?(B).y:(S)==6?(B).z:(B).w)

    // dot slice S: lane j accumulates dimension S of its step-j projection
#define DOT_SLICE(S, LA, LB, PRZ, PN)                                         \
    { const float xv_ = GETF(S, LA, LB);                                      \
      if ((S) == 0) { PRZ = wrz[0] * (v2f){xv_, xv_} + B0rz;                  \
                      PN  = fmaf(xv_, wn[0], B0n); }                          \
      else          { PRZ = wrz[S] * (v2f){xv_, xv_} + PRZ;                   \
                      PN  = fmaf(xv_, wn[S], PN); } }

    // preselect slot S: static shl:S brings proj(step S) to lane 8g; others B1
#define PRESEL(S, SRZ, SN, PRZs, PNs)                                         \
    { const float br_ = DPPSHLX(S, (PRZs).x);                                 \
      const float bz_ = DPPSHLX(S, (PRZs).y);                                 \
      const float bn_ = DPPSHLX(S, (PNs));                                    \
      SRZ[S] = (v2f){lz ? br_ : B1r, lz ? bz_ : B1z};                         \
      SN[S]  = lz ? bn_ : B1n; }

    auto step1 = [&](int i, v2f brz, float bn, bool guard) {
        const float nbr = dpp_shr1(h);

        const v2f t12 = WH12 * (v2f){h, h} + brz;
        const v2f arz = W1rz * (v2f){nbr, nbr} + t12;
        const float er = __builtin_amdgcn_exp2f(arz.x);
        const float ez = __builtin_amdgcn_exp2f(arz.y);
        const float r  = __builtin_amdgcn_rcpf(1.0f + er);
        const float pz1 = 1.0f + ez;

        const v2f tnx = (v2f){whpn, W1n} * (v2f){h, nbr} + (v2f){bhpn, bn};
        const float na = fmaf(r, tnx.x, tnx.y);
        const float en = __builtin_amdgcn_exp2f(na);

        const float P  = fmaf(en, pz1, pz1);           // (1+en)(1+ez)
        const float R  = __builtin_amdgcn_rcpf(P);     // merged z+n rcp
        const float hp1 = h + 1.0f;
        const float hm1 = 1.0f - h;
        const float q  = fmaf(-hp1, en, hm1);
        const float hn = fmaf(R, q, h);                // h + R*q

        if (guard) {
            h = ((unsigned)(i - l) < (unsigned)T_LEN) ? hn : h;
        } else {
            h = hn;
        }
    };

    // fused step: chain + dot slice (chunk c+2) + presel slot (chunk c+1)
#define STEPX(S, C, SRr, SNr, SRw, SNw, PZr_rz, PZr_n, PZw_rz, PZw_n,         \
              LNa, LNb, GD)                                                   \
    { step1((C) * 8 + (S), SRr[S], SNr[S], GD);                               \
      DOT_SLICE(S, LNa, LNb, PZw_rz, PZw_n)                                   \
      PRESEL(S, SRw, SNw, PZr_rz, PZr_n) }

#define RUN_CHUNK(C, SRr, SNr, SRw, SNw, PZr_rz, PZr_n, PZw_rz, PZw_n,        \
                  LNa, LNb, LlA, LlB, C4, GD)                                 \
    { LOADL(LlA, LlB, C4)                                                     \
      STEPX(0, C, SRr, SNr, SRw, SNw, PZr_rz, PZr_n, PZw_rz, PZw_n, LNa, LNb, GD) \
      STEPX(1, C, SRr, SNr, SRw, SNw, PZr_rz, PZr_n, PZw_rz, PZw_n, LNa, LNb, GD) \
      STEPX(2, C, SRr, SNr, SRw, SNw, PZr_rz, PZr_n, PZw_rz, PZw_n, LNa, LNb, GD) \
      STEPX(3, C, SRr, SNr, SRw, SNw, PZr_rz, PZr_n, PZw_rz, PZw_n, LNa, LNb, GD) \
      STEPX(4, C, SRr, SNr, SRw, SNw, PZr_rz, PZr_n, PZw_rz, PZw_n, LNa, LNb, GD) \
      STEPX(5, C, SRr, SNr, SRw, SNw, PZr_rz, PZr_n, PZw_rz, PZw_n, LNa, LNb, GD) \
      STEPX(6, C, SRr, SNr, SRw, SNw, PZr_rz, PZr_n, PZw_rz, PZw_n, LNa, LNb, GD) \
      STEPX(7, C, SRr, SNr, SRw, SNw, PZr_rz, PZr_n, PZw_rz, PZw_n, LNa, LNb, GD) }

    // ---- prologue: L0..L3 <- chunks 0..3; dots(0)->PZA, dots(1)->PZB;
    //      presel(0)->SA ----
    LOADL(L0a, L0b, 0) LOADL(L1a, L1b, 1) LOADL(L2a, L2b, 2) LOADL(L3a, L3b, 3)

    DOT_SLICE(0, L0a, L0b, PZArz, PZAn) DOT_SLICE(1, L0a, L0b, PZArz, PZAn)
    DOT_SLICE(2, L0a, L0b, PZArz, PZAn) DOT_SLICE(3, L0a, L0b, PZArz, PZAn)
    DOT_SLICE(4, L0a, L0b, PZArz, PZAn) DOT_SLICE(5, L0a, L0b, PZArz, PZAn)
    DOT_SLICE(6, L0a, L0b, PZArz, PZAn) DOT_SLICE(7, L0a, L0b, PZArz, PZAn)

    DOT_SLICE(0, L1a, L1b, PZBrz, PZBn) DOT_SLICE(1, L1a, L1b, PZBrz, PZBn)
    DOT_SLICE(2, L1a, L1b, PZBrz, PZBn) DOT_SLICE(3, L1a, L1b, PZBrz, PZBn)
    DOT_SLICE(4, L1a, L1b, PZBrz, PZBn) DOT_SLICE(5, L1a, L1b, PZBrz, PZBn)
    DOT_SLICE(6, L1a, L1b, PZBrz, PZBn) DOT_SLICE(7, L1a, L1b, PZBrz, PZBn)

    PRESEL(0, SrzA, SnA, PZArz, PZAn) PRESEL(1, SrzA, SnA, PZArz, PZAn)
    PRESEL(2, SrzA, SnA, PZArz, PZAn) PRESEL(3, SrzA, SnA, PZArz, PZAn)
    PRESEL(4, SrzA, SnA, PZArz, PZAn) PRESEL(5, SrzA, SnA, PZArz, PZAn)
    PRESEL(6, SrzA, SnA, PZArz, PZAn) PRESEL(7, SrzA, SnA, PZArz, PZAn)

    // ---- chunks 0..3 (chunk 0 guarded) ----
    RUN_CHUNK(0, SrzA, SnA, SrzB, SnB, PZBrz, PZBn, PZArz, PZAn, L2a, L2b, L0a, L0b, 4, true)
    RUN_CHUNK(1, SrzB, SnB, SrzA, SnA, PZArz, PZAn, PZBrz, PZBn, L3a, L3b, L1a, L1b, 5, false)
    RUN_CHUNK(2, SrzA, SnA, SrzB, SnB, PZBrz, PZBn, PZArz, PZAn, L0a, L0b, L2a, L2b, 6, false)
    RUN_CHUNK(3, SrzB, SnB, SrzA, SnA, PZArz, PZAn, PZBrz, PZBn, L1a, L1b, L3a, L3b, 7, false)

    #pragma unroll 1
    for (int q = 1; q < 64; ++q) {
        const int c0 = q * 4;
        RUN_CHUNK(c0 + 0, SrzA, SnA, SrzB, SnB, PZBrz, PZBn, PZArz, PZAn, L2a, L2b, L0a, L0b, c0 + 4, false)
        RUN_CHUNK(c0 + 1, SrzB, SnB, SrzA, SnA, PZArz, PZAn, PZBrz, PZBn, L3a, L3b, L1a, L1b, c0 + 5, false)
        RUN_CHUNK(c0 + 2, SrzA, SnA, SrzB, SnB, PZBrz, PZBn, PZArz, PZAn, L0a, L0b, L2a, L2b, c0 + 6, false)
        RUN_CHUNK(c0 + 3, SrzB, SnB, SrzA, SnA, PZArz, PZAn, PZBrz, PZBn, L1a, L1b, L3a, L3b, c0 + 7, false)
    }

    // tail: 5 guarded steps, no x (layer 0 frozen; layers 1..5 finish)
    #pragma unroll
    for (int i = T_LEN; i < T_LEN + 5; ++i) step1(i, B1rz, B1n, true);

    if (l == 5) out[b] = h;          // layer-5 h frozen at t = T-1
}

extern "C" void kernel_launch(void* const* d_in, const int* in_sizes, int n_in,
                              void* d_out, int out_size, void* d_ws, size_t ws_size,
                              hipStream_t stream) {
    const float* x     = (const float*)d_in[0];
    const float* Wih0  = (const float*)d_in[1];
    const float* Wrest = (const float*)d_in[2];
    const float* Whh   = (const float*)d_in[3];
    const float* bih   = (const float*)d_in[4];
    const float* bhh   = (const float*)d_in[5];
    float* out = (float*)d_out;

    gru_scan<<<512, 64, 0, stream>>>(x, Wih0, Wrest, Whh, bih, bhh, out);
}